// Round 1
// baseline (741.699 us; speedup 1.0000x reference)
//
#include <hip/hip_runtime.h>

// SpectralMapDecomposition:
//   sep[b,i,h,w] = (1/256) * ( ReC[b,h,i]*cos(2*pi*i*w/256) - ImC[b,h,i]*sin(2*pi*i*w/256) )
//   where C[b,h,i] = sum_x img[b,h,x] * exp(-2*pi*j*i*x/256)
//   out = concat([sep (256 ch), mask (32 ch)], axis=1)  -> (8, 288, 256, 256) fp32
//
// HBM-write bound: 604 MB output. Three stream-ordered kernels:
//   1) dft_rows:  2048 blocks, per-row 256-pt DFT, stores C/256 transposed [b][i][h]
//      (stashed inside d_out's b=0 mask-channel region; overwritten last by mask_copy)
//   2) expand:    2048 blocks = (b,i); LDS-staged C column; float4 coalesced stores
//   3) mask_copy: float4 copy of mask channels (runs last -> reclaims the stash)

#define TWO_PI_OVER_256 0.02454369260617026f

__global__ __launch_bounds__(256) void dft_rows_kernel(const float* __restrict__ img,
                                                       float2* __restrict__ Ct) {
    __shared__ float row[256];
    __shared__ float ct[256];
    __shared__ float st[256];
    const int t  = threadIdx.x;
    const int bh = blockIdx.x;                 // b*256 + h
    row[t] = img[(size_t)bh * 256 + t];
    float s, c;
    __sincosf((float)t * TWO_PI_OVER_256, &s, &c);
    ct[t] = c;
    st[t] = s;
    __syncthreads();

    // thread t computes frequency i = t for this row; twiddle index is exact:
    // angle(i,x) = 2*pi*((i*x) mod 256)/256, walked incrementally k += t (mod 256)
    float re = 0.f, im = 0.f;
    int k = 0;
#pragma unroll 8
    for (int x = 0; x < 256; ++x) {
        const float r = row[x];
        re = fmaf(r, ct[k], re);
        im = fmaf(r, st[k], im);               // accumulates +sum(r*sin); negate below
        k = (k + t) & 255;
    }
    const int b = bh >> 8;
    const int h = bh & 255;
    // transposed layout Ct[b][i][h] so the expand kernel reads coalesced
    Ct[((size_t)(b * 256 + t)) * 256 + h] =
        make_float2(re * (1.f / 256.f), im * (-1.f / 256.f));
}

__global__ __launch_bounds__(256) void expand_kernel(const float2* __restrict__ Ct,
                                                     float* __restrict__ out) {
    const int t   = threadIdx.x;
    const int blk = blockIdx.x;                // b*256 + i
    const int b   = blk >> 8;
    const int i   = blk & 255;

    __shared__ float2 cp[256];                 // C[b, h=0..255, i] (pre-scaled by 1/256)
    cp[t] = Ct[(size_t)blk * 256 + t];         // coalesced 8B loads

    // each thread owns 4 consecutive w; its cos/sin live in registers for all h
    const int wb = (t & 63) * 4;
    float cw[4], sw[4];
#pragma unroll
    for (int j = 0; j < 4; ++j) {
        const int k = (i * (wb + j)) & 255;    // exact twiddle index
        __sincosf((float)k * TWO_PI_OVER_256, &sw[j], &cw[j]);
    }
    __syncthreads();

    const int hl = t >> 6;                     // 4 h-rows in flight per iteration
    float* __restrict__ obase = out + ((size_t)b * 288 + i) * 65536;
#pragma unroll 4
    for (int it = 0; it < 64; ++it) {
        const int h = it * 4 + hl;
        const float2 cv = cp[h];               // LDS broadcast within each 64-lane team
        float4 v;
        v.x = cv.x * cw[0] - cv.y * sw[0];
        v.y = cv.x * cw[1] - cv.y * sw[1];
        v.z = cv.x * cw[2] - cv.y * sw[2];
        v.w = cv.x * cw[3] - cv.y * sw[3];
        *reinterpret_cast<float4*>(obase + (size_t)h * 256 + wb) = v;  // 4KB/block/iter contiguous
    }
}

__global__ __launch_bounds__(256) void mask_copy_kernel(const float4* __restrict__ m,
                                                        float4* __restrict__ out) {
    const size_t e = (size_t)blockIdx.x * 256 + threadIdx.x;  // 0 .. 4194303 (float4 units)
    const size_t b = e >> 19;                                 // 524288 float4 per batch of mask
    const size_t r = e & 524287;
    out[b * 4718592 + 4194304 + r] = m[b * 524288 + r];       // 288ch stride, skip 256 sep ch
}

extern "C" void kernel_launch(void* const* d_in, const int* in_sizes, int n_in,
                              void* d_out, int out_size, void* d_ws, size_t ws_size,
                              hipStream_t stream) {
    const float* img  = (const float*)d_in[0];   // (8,1,256,256) fp32
    const float* mask = (const float*)d_in[1];   // (8,32,256,256) fp32
    float* out = (float*)d_out;                  // (8,288,256,256) fp32

    // Stash C (4 MB) inside d_out's b=0 mask-channel region [256*65536, 288*65536):
    // expand never writes there (it writes only sep channels), and mask_copy_kernel
    // overwrites it last in stream order. No dependence on ws_size.
    float2* Ct = (float2*)(out + (size_t)256 * 65536);

    dft_rows_kernel<<<2048, 256, 0, stream>>>(img, Ct);
    expand_kernel<<<2048, 256, 0, stream>>>(Ct, out);
    mask_copy_kernel<<<16384, 256, 0, stream>>>((const float4*)mask, (float4*)out);
}